// Round 14
// baseline (610.334 us; speedup 1.0000x reference)
//
#include <hip/hip_runtime.h>

#define N_NODES 100000
#define N_EDGES 3200000
#define N_GRAPHS 512
#define VOCAB 128
#define HID 16
#define LABELS 10
#define NCOPY 8                 // replication for histogram atomics
#define SCAN_NB 98              // ceil(100000/1024)

// in-degree histogram, NCOPY-way replicated to cut same-address contention
__global__ void k_hist(const int* __restrict__ dst, int* __restrict__ icnt) {
    int e = blockIdx.x * blockDim.x + threadIdx.x;
    if (e < N_EDGES) atomicAdd(&icnt[(blockIdx.x & (NCOPY - 1)) * N_NODES + dst[e]], 1);
}

// phase 1: merge copies -> deg, dinv=rsqrt(deg+1), block-local exclusive scan -> row,
// per-block total -> blocksum. 98 blocks x 1024 threads.
__global__ void k_merge_scan1(const int* __restrict__ icnt, int* __restrict__ row,
                              float* __restrict__ dinv, int* __restrict__ blocksum) {
    int t = threadIdx.x;
    int n = blockIdx.x * 1024 + t;
    int tot = 0;
    if (n < N_NODES) {
#pragma unroll
        for (int c = 0; c < NCOPY; ++c) tot += icnt[c * N_NODES + n];
        dinv[n] = rsqrtf((float)tot + 1.0f);   // +1 = self-loop
    }
    __shared__ int s[1024];
    s[t] = tot;
    __syncthreads();
    for (int off = 1; off < 1024; off <<= 1) {
        int v = (t >= off) ? s[t - off] : 0;
        __syncthreads();
        s[t] += v;
        __syncthreads();
    }
    if (n < N_NODES) row[n] = s[t] - tot;      // exclusive within block
    if (t == 1023) blocksum[blockIdx.x] = s[1023];
}

// phase 2: exclusive scan of the 98 block sums (single small block)
__global__ void k_scanblocks(int* __restrict__ blocksum, int* __restrict__ boff) {
    int t = threadIdx.x;
    int v = (t < SCAN_NB) ? blocksum[t] : 0;
    __shared__ int s[128];
    s[t] = v;
    __syncthreads();
    for (int off = 1; off < 128; off <<= 1) {
        int u = (t >= off) ? s[t - off] : 0;
        __syncthreads();
        s[t] += u;
        __syncthreads();
    }
    if (t < SCAN_NB) boff[t] = s[t] - v;       // exclusive
}

// phase 3: finalize row with block offset; cursor copy; pack (x, dinv) per node
__global__ void k_cursor(int* __restrict__ cursor, int* __restrict__ row,
                         const int* __restrict__ boff, const int* __restrict__ x,
                         const float* __restrict__ dinv, int2* __restrict__ xd) {
    int n = blockIdx.x * blockDim.x + threadIdx.x;
    if (n >= N_NODES) return;
    int run = row[n] + boff[n >> 10];
    row[n] = run;
    cursor[n] = run;
    xd[n] = make_int2(x[n], __float_as_int(dinv[n]));
    if (n == 0) row[N_NODES] = N_EDGES;        // grand total is static
}

// single-pass scatter. gfx950 atomics write through TCC at dword granularity
// (R3 evidence: WRITE_SIZE == atomics*4B exactly), so issuing the csr store as
// atomicExch writes 4 B instead of dirtying a 64 B line that would write back
// partially filled. No L2 residency needed -> no XCD partitioning, dst/src
// read ONCE (nt, evict-first).
__global__ void k_scatter(const int* __restrict__ src, const int* __restrict__ dst,
                          int* __restrict__ cursor, int* __restrict__ csr) {
    int e = blockIdx.x * 256 + threadIdx.x;
    if (e >= N_EDGES) return;
    int d = __builtin_nontemporal_load(&dst[e]);
    int s = __builtin_nontemporal_load(&src[e]);
    int slot = atomicAdd(&cursor[d], 1);
    atomicExch(&csr[slot], s);
}

// table = emb @ W1 (128 x 16)
__global__ void k_table(const float* __restrict__ emb, const float* __restrict__ W1,
                        float* __restrict__ table) {
    int t = blockIdx.x * blockDim.x + threadIdx.x;
    if (t >= VOCAB * HID) return;
    int v = t / HID, k = t % HID;
    float acc = 0.f;
    for (int j = 0; j < HID; ++j) acc += emb[v * HID + j] * W1[j * HID + k];
    table[t] = acc;
}

// layer-1 aggregation exploiting hws1[s] = table[x[s]] * dinv[s] with only 128
// distinct table rows: stage table in LDS (8 KB), gather just 8 B (x,dinv) per
// edge from an 800 KB L2-resident array. out[n] = dinv[n]*(self + sum_s ...)
__global__ void k_gather_t(const int* __restrict__ row, const int* __restrict__ csr,
                           const int2* __restrict__ xd, const float* __restrict__ table,
                           float* __restrict__ out) {
    __shared__ float tbl[VOCAB * HID];
    for (int i = threadIdx.x; i < VOCAB * HID; i += 256) tbl[i] = table[i];
    __syncthreads();
    int t = blockIdx.x * 256 + threadIdx.x;
    int n = t >> 4, k = t & 15;
    if (n >= N_NODES) return;
    int2 self = xd[n];
    float dvn = __int_as_float(self.y);
    float acc = tbl[self.x * HID + k] * dvn;   // self-loop hws1
    int lo = row[n], hi = row[n + 1];
    int i = lo;
    for (; i + 4 <= hi; i += 4) {
        int s0 = csr[i], s1 = csr[i + 1], s2 = csr[i + 2], s3 = csr[i + 3];
        int2 a0 = xd[s0], a1 = xd[s1], a2 = xd[s2], a3 = xd[s3];
        acc += tbl[a0.x * HID + k] * __int_as_float(a0.y);
        acc += tbl[a1.x * HID + k] * __int_as_float(a1.y);
        acc += tbl[a2.x * HID + k] * __int_as_float(a2.y);
        acc += tbl[a3.x * HID + k] * __int_as_float(a3.y);
    }
    for (; i < hi; ++i) {
        int2 a = xd[csr[i]];
        acc += tbl[a.x * HID + k] * __int_as_float(a.y);
    }
    out[n * HID + k] = acc * dvn;
}

// layer-2 aggregation: out[n] = dinv[n] * (hws[n] + sum hws[s]); 16 lanes/node,
// x4 unroll for 4 independent row-gathers in flight.
__global__ void k_gather(const int* __restrict__ row, const int* __restrict__ csr,
                         const float* __restrict__ dinv, const float* __restrict__ hws,
                         float* __restrict__ out) {
    int t = blockIdx.x * blockDim.x + threadIdx.x;
    int n = t >> 4, k = t & 15;
    if (n >= N_NODES) return;
    float acc = hws[n * HID + k];              // self-loop term (pre-scaled)
    int lo = row[n], hi = row[n + 1];
    int i = lo;
    for (; i + 4 <= hi; i += 4) {
        int s0 = csr[i], s1 = csr[i + 1], s2 = csr[i + 2], s3 = csr[i + 3];
        float a0 = hws[s0 * HID + k], a1 = hws[s1 * HID + k];
        float a2 = hws[s2 * HID + k], a3 = hws[s3 * HID + k];
        acc += a0; acc += a1; acc += a2; acc += a3;
    }
    for (; i < hi; ++i) acc += hws[csr[i] * HID + k];
    out[n * HID + k] = acc * dinv[n];
}

// h1 = relu(out + b1); hws2 = (h1 @ W2) * dinv[n]
__global__ void k_update(const float* __restrict__ out, float* __restrict__ hws,
                         const float* __restrict__ dinv,
                         const float* __restrict__ b1, const float* __restrict__ W2) {
    __shared__ float sW[HID * HID];
    __shared__ float sb[HID];
    int lt = threadIdx.x;
    if (lt < HID * HID) sW[lt] = W2[lt];
    if (lt < HID) sb[lt] = b1[lt];
    __syncthreads();
    int n = blockIdx.x * blockDim.x + lt;
    if (n >= N_NODES) return;
    float h[HID];
#pragma unroll
    for (int j = 0; j < HID; ++j) h[j] = fmaxf(out[n * HID + j] + sb[j], 0.f);
    float dv = dinv[n];
#pragma unroll
    for (int k = 0; k < HID; ++k) {
        float acc = 0.f;
#pragma unroll
        for (int j = 0; j < HID; ++j) acc += h[j] * sW[j * HID + k];
        hws[n * HID + k] = acc * dv;
    }
}

__device__ __forceinline__ int lower_bound_i(const int* a, int n, int key) {
    int lo = 0, hi = n;
    while (lo < hi) { int mid = (lo + hi) >> 1; if (a[mid] < key) lo = mid + 1; else hi = mid; }
    return lo;
}

// one block per graph (batch sorted): relu(out+b2), mean-pool, logits; no atomics
__global__ void k_pool(const float* __restrict__ out, const int* __restrict__ batch,
                       const float* __restrict__ b2, const float* __restrict__ Wc,
                       const float* __restrict__ bc, float* __restrict__ outp) {
    int g = blockIdx.x;
    __shared__ int s_lo, s_hi;
    if (threadIdx.x == 0) {
        s_lo = lower_bound_i(batch, N_NODES, g);
        s_hi = lower_bound_i(batch, N_NODES, g + 1);
    }
    __syncthreads();
    int lo = s_lo, hi = s_hi;
    int k = threadIdx.x & 15, j = threadIdx.x >> 4;   // 16 node-slots x 16 features
    float acc = 0.f;
    for (int n = lo + j; n < hi; n += 16)
        acc += fmaxf(out[n * HID + k] + b2[k], 0.f);
    __shared__ float red[16][HID + 1];
    red[j][k] = acc;
    __syncthreads();
    __shared__ float pooled[HID];
    if (threadIdx.x < HID) {
        float s = 0.f;
#pragma unroll
        for (int jj = 0; jj < 16; ++jj) s += red[jj][threadIdx.x];
        pooled[threadIdx.x] = s / fmaxf((float)(hi - lo), 1.0f);
    }
    __syncthreads();
    if (threadIdx.x < LABELS) {
        float accl = bc[threadIdx.x];
#pragma unroll
        for (int kk = 0; kk < HID; ++kk) accl += pooled[kk] * Wc[kk * LABELS + threadIdx.x];
        outp[g * LABELS + threadIdx.x] = accl;
    }
}

extern "C" void kernel_launch(void* const* d_in, const int* in_sizes, int n_in,
                              void* d_out, int out_size, void* d_ws, size_t ws_size,
                              hipStream_t stream) {
    const int*   x     = (const int*)d_in[0];
    const int*   ei    = (const int*)d_in[1];
    const int*   batch = (const int*)d_in[2];
    const float* emb   = (const float*)d_in[3];
    const float* W1    = (const float*)d_in[4];
    const float* b1    = (const float*)d_in[5];
    const float* W2    = (const float*)d_in[6];
    const float* b2    = (const float*)d_in[7];
    const float* Wc    = (const float*)d_in[8];
    const float* bc    = (const float*)d_in[9];
    float* outp = (float*)d_out;

    // workspace layout: ~31 MB
    int*   icnt = (int*)d_ws;                          // NCOPY*N_NODES (hist; [0] reused as cursor)
    int*   row  = icnt + (size_t)NCOPY * N_NODES;      // N_NODES+1
    int*   csr  = row + (N_NODES + 1);                 // N_EDGES (src per CSR slot)
    float* dinv = (float*)(csr + N_EDGES);             // N_NODES
    float* hws  = dinv + N_NODES;                      // N_NODES*HID (layer-2 pre-scaled hw)
    float* out  = hws + (size_t)N_NODES * HID;         // N_NODES*HID
    float* table= out + (size_t)N_NODES * HID;         // VOCAB*HID
    int*   bsum = (int*)(table + VOCAB * HID);         // SCAN_NB
    int*   boff = bsum + SCAN_NB;                      // SCAN_NB
    int2*  xd   = (int2*)(((uintptr_t)(boff + SCAN_NB) + 15) & ~(uintptr_t)15); // N_NODES

    const int* srcp = ei;            // edge_index row 0
    const int* dstp = ei + N_EDGES;  // edge_index row 1

    (void)hipMemsetAsync(icnt, 0, (size_t)NCOPY * N_NODES * sizeof(int), stream);

    const int EBLK = (N_EDGES + 255) / 256;            // 12500
    k_hist       <<<EBLK, 256, 0, stream>>>(dstp, icnt);
    k_merge_scan1<<<SCAN_NB, 1024, 0, stream>>>(icnt, row, dinv, bsum);
    k_scanblocks <<<1, 128, 0, stream>>>(bsum, boff);
    k_cursor     <<<(N_NODES + 255) / 256, 256, 0, stream>>>(icnt, row, boff, x, dinv, xd);
    k_scatter    <<<EBLK, 256, 0, stream>>>(srcp, dstp, icnt, csr);
    k_table      <<<(VOCAB * HID + 255) / 256, 256, 0, stream>>>(emb, W1, table);
    k_gather_t   <<<(N_NODES * HID + 255) / 256, 256, 0, stream>>>(row, csr, xd, table, out);
    k_update     <<<(N_NODES + 255) / 256, 256, 0, stream>>>(out, hws, dinv, b1, W2);
    k_gather     <<<(N_NODES * HID + 255) / 256, 256, 0, stream>>>(row, csr, dinv, hws, out);
    k_pool       <<<N_GRAPHS, 256, 0, stream>>>(out, batch, b2, Wc, bc, outp);
}

// Round 15
// 466.442 us; speedup vs baseline: 1.3085x; 1.3085x over previous
//
#include <hip/hip_runtime.h>

#define N_NODES 100000
#define N_EDGES 3200000
#define N_GRAPHS 512
#define VOCAB 128
#define HID 16
#define LABELS 10
#define NCOPY 8                 // replication for histogram atomics
#define SCAN_NB 98              // ceil(100000/1024)
#define NPART 4                 // dst partitions (each owned by 2 XCDs; byte-masked
                                // writebacks make multi-XCD windows safe — R5 evidence)
#define PART_SZ (N_NODES / NPART)   // 25000

// in-degree histogram, NCOPY-way replicated to cut same-address contention
__global__ void k_hist(const int* __restrict__ dst, int* __restrict__ icnt) {
    int e = blockIdx.x * blockDim.x + threadIdx.x;
    if (e < N_EDGES) atomicAdd(&icnt[(blockIdx.x & (NCOPY - 1)) * N_NODES + dst[e]], 1);
}

// phase 1: merge copies -> deg, dinv=rsqrt(deg+1), block-local exclusive scan -> row,
// per-block total -> blocksum. 98 blocks x 1024 threads.
__global__ void k_merge_scan1(const int* __restrict__ icnt, int* __restrict__ row,
                              float* __restrict__ dinv, int* __restrict__ blocksum) {
    int t = threadIdx.x;
    int n = blockIdx.x * 1024 + t;
    int tot = 0;
    if (n < N_NODES) {
#pragma unroll
        for (int c = 0; c < NCOPY; ++c) tot += icnt[c * N_NODES + n];
        dinv[n] = rsqrtf((float)tot + 1.0f);   // +1 = self-loop
    }
    __shared__ int s[1024];
    s[t] = tot;
    __syncthreads();
    for (int off = 1; off < 1024; off <<= 1) {
        int v = (t >= off) ? s[t - off] : 0;
        __syncthreads();
        s[t] += v;
        __syncthreads();
    }
    if (n < N_NODES) row[n] = s[t] - tot;      // exclusive within block
    if (t == 1023) blocksum[blockIdx.x] = s[1023];
}

// phase 2: exclusive scan of the 98 block sums (single small block)
__global__ void k_scanblocks(int* __restrict__ blocksum, int* __restrict__ boff) {
    int t = threadIdx.x;
    int v = (t < SCAN_NB) ? blocksum[t] : 0;
    __shared__ int s[128];
    s[t] = v;
    __syncthreads();
    for (int off = 1; off < 128; off <<= 1) {
        int u = (t >= off) ? s[t - off] : 0;
        __syncthreads();
        s[t] += u;
        __syncthreads();
    }
    if (t < SCAN_NB) boff[t] = s[t] - v;       // exclusive
}

// phase 3: finalize row with block offset; cursor copy; pack (x, dinv) per node
__global__ void k_cursor(int* __restrict__ cursor, int* __restrict__ row,
                         const int* __restrict__ boff, const int* __restrict__ x,
                         const float* __restrict__ dinv, int2* __restrict__ xd) {
    int n = blockIdx.x * blockDim.x + threadIdx.x;
    if (n >= N_NODES) return;
    int run = row[n] + boff[n >> 10];
    row[n] = run;
    cursor[n] = run;
    xd[n] = make_int2(x[n], __float_as_int(dinv[n]));
    if (n == 0) row[N_NODES] = N_EDGES;        // grand total is static
}

// dst-partitioned scatter: block b -> edge chunk b>>2, dst range (b&3)*25000..+25000.
// nt on dst/src keeps the read streams out of L2 so csr write-lines stay resident;
// 4 passes instead of 8 halves the L3-bypassing re-read cost.
__global__ void k_scatter(const int* __restrict__ src, const int* __restrict__ dst,
                          int* __restrict__ cursor, int* __restrict__ csr) {
    int part  = blockIdx.x & (NPART - 1);
    int chunk = blockIdx.x >> 2;
    int e = chunk * 256 + threadIdx.x;
    if (e >= N_EDGES) return;
    int d = __builtin_nontemporal_load(&dst[e]);
    if ((unsigned)(d - part * PART_SZ) < (unsigned)PART_SZ) {
        int slot = atomicAdd(&cursor[d], 1);
        csr[slot] = __builtin_nontemporal_load(&src[e]);
    }
}

// table = emb @ W1 (128 x 16)
__global__ void k_table(const float* __restrict__ emb, const float* __restrict__ W1,
                        float* __restrict__ table) {
    int t = blockIdx.x * blockDim.x + threadIdx.x;
    if (t >= VOCAB * HID) return;
    int v = t / HID, k = t % HID;
    float acc = 0.f;
    for (int j = 0; j < HID; ++j) acc += emb[v * HID + j] * W1[j * HID + k];
    table[t] = acc;
}

// FUSED layer-1 aggregation + update:
//  out1[n,k] = dvn*(tbl[x[n],k]*dvn + sum_s tbl[x[s],k]*dinv[s])  (table in LDS,
//  per-edge gather is just 8 B xd from an 800 KB L2-resident array)
//  h1 = relu(out1 + b1);  hws2[n,:] = (h1 @ W2) * dvn   via LDS feature exchange.
// Grid is exactly N_NODES*HID/256 = 6250 blocks: no bounds guards needed.
__global__ void k_gather_t(const int* __restrict__ row, const int* __restrict__ csr,
                           const int2* __restrict__ xd, const float* __restrict__ table,
                           const float* __restrict__ b1, const float* __restrict__ W2,
                           float* __restrict__ hws) {
    __shared__ float tbl[VOCAB * HID];
    __shared__ float sW[HID * HID];
    __shared__ float sb[HID];
    __shared__ float sh[16][HID + 1];
    for (int i = threadIdx.x; i < VOCAB * HID; i += 256) tbl[i] = table[i];
    if (threadIdx.x < HID * HID) sW[threadIdx.x] = W2[threadIdx.x];
    if (threadIdx.x < HID) sb[threadIdx.x] = b1[threadIdx.x];
    __syncthreads();
    int t = blockIdx.x * 256 + threadIdx.x;
    int n = t >> 4, k = t & 15, nl = threadIdx.x >> 4;
    int2 self = xd[n];
    float dvn = __int_as_float(self.y);
    float acc = tbl[self.x * HID + k] * dvn;   // self-loop hws1
    int lo = row[n], hi = row[n + 1];
    int i = lo;
    for (; i + 4 <= hi; i += 4) {
        int s0 = csr[i], s1 = csr[i + 1], s2 = csr[i + 2], s3 = csr[i + 3];
        int2 a0 = xd[s0], a1 = xd[s1], a2 = xd[s2], a3 = xd[s3];
        acc += tbl[a0.x * HID + k] * __int_as_float(a0.y);
        acc += tbl[a1.x * HID + k] * __int_as_float(a1.y);
        acc += tbl[a2.x * HID + k] * __int_as_float(a2.y);
        acc += tbl[a3.x * HID + k] * __int_as_float(a3.y);
    }
    for (; i < hi; ++i) {
        int2 a = xd[csr[i]];
        acc += tbl[a.x * HID + k] * __int_as_float(a.y);
    }
    sh[nl][k] = fmaxf(acc * dvn + sb[k], 0.f); // h1[n,k]
    __syncthreads();
    float o = 0.f;
#pragma unroll
    for (int j = 0; j < HID; ++j) o += sh[nl][j] * sW[j * HID + k];
    hws[n * HID + k] = o * dvn;                // pre-scaled layer-2 input
}

// layer-2 aggregation: out[n] = dinv[n] * (hws[n] + sum hws[s]); 16 lanes/node,
// x4 unroll for 4 independent row-gathers in flight.
__global__ void k_gather(const int* __restrict__ row, const int* __restrict__ csr,
                         const float* __restrict__ dinv, const float* __restrict__ hws,
                         float* __restrict__ out) {
    int t = blockIdx.x * blockDim.x + threadIdx.x;
    int n = t >> 4, k = t & 15;
    if (n >= N_NODES) return;
    float acc = hws[n * HID + k];              // self-loop term (pre-scaled)
    int lo = row[n], hi = row[n + 1];
    int i = lo;
    for (; i + 4 <= hi; i += 4) {
        int s0 = csr[i], s1 = csr[i + 1], s2 = csr[i + 2], s3 = csr[i + 3];
        float a0 = hws[s0 * HID + k], a1 = hws[s1 * HID + k];
        float a2 = hws[s2 * HID + k], a3 = hws[s3 * HID + k];
        acc += a0; acc += a1; acc += a2; acc += a3;
    }
    for (; i < hi; ++i) acc += hws[csr[i] * HID + k];
    out[n * HID + k] = acc * dinv[n];
}

__device__ __forceinline__ int lower_bound_i(const int* a, int n, int key) {
    int lo = 0, hi = n;
    while (lo < hi) { int mid = (lo + hi) >> 1; if (a[mid] < key) lo = mid + 1; else hi = mid; }
    return lo;
}

// one block per graph (batch sorted): relu(out+b2), mean-pool, logits; no atomics
__global__ void k_pool(const float* __restrict__ out, const int* __restrict__ batch,
                       const float* __restrict__ b2, const float* __restrict__ Wc,
                       const float* __restrict__ bc, float* __restrict__ outp) {
    int g = blockIdx.x;
    __shared__ int s_lo, s_hi;
    if (threadIdx.x == 0) {
        s_lo = lower_bound_i(batch, N_NODES, g);
        s_hi = lower_bound_i(batch, N_NODES, g + 1);
    }
    __syncthreads();
    int lo = s_lo, hi = s_hi;
    int k = threadIdx.x & 15, j = threadIdx.x >> 4;   // 16 node-slots x 16 features
    float acc = 0.f;
    for (int n = lo + j; n < hi; n += 16)
        acc += fmaxf(out[n * HID + k] + b2[k], 0.f);
    __shared__ float red[16][HID + 1];
    red[j][k] = acc;
    __syncthreads();
    __shared__ float pooled[HID];
    if (threadIdx.x < HID) {
        float s = 0.f;
#pragma unroll
        for (int jj = 0; jj < 16; ++jj) s += red[jj][threadIdx.x];
        pooled[threadIdx.x] = s / fmaxf((float)(hi - lo), 1.0f);
    }
    __syncthreads();
    if (threadIdx.x < LABELS) {
        float accl = bc[threadIdx.x];
#pragma unroll
        for (int kk = 0; kk < HID; ++kk) accl += pooled[kk] * Wc[kk * LABELS + threadIdx.x];
        outp[g * LABELS + threadIdx.x] = accl;
    }
}

extern "C" void kernel_launch(void* const* d_in, const int* in_sizes, int n_in,
                              void* d_out, int out_size, void* d_ws, size_t ws_size,
                              hipStream_t stream) {
    const int*   x     = (const int*)d_in[0];
    const int*   ei    = (const int*)d_in[1];
    const int*   batch = (const int*)d_in[2];
    const float* emb   = (const float*)d_in[3];
    const float* W1    = (const float*)d_in[4];
    const float* b1    = (const float*)d_in[5];
    const float* W2    = (const float*)d_in[6];
    const float* b2    = (const float*)d_in[7];
    const float* Wc    = (const float*)d_in[8];
    const float* bc    = (const float*)d_in[9];
    float* outp = (float*)d_out;

    // workspace layout: ~31 MB
    int*   icnt = (int*)d_ws;                          // NCOPY*N_NODES (hist; [0] reused as cursor)
    int*   row  = icnt + (size_t)NCOPY * N_NODES;      // N_NODES+1
    int*   csr  = row + (N_NODES + 1);                 // N_EDGES (src per CSR slot)
    float* dinv = (float*)(csr + N_EDGES);             // N_NODES
    float* hws  = dinv + N_NODES;                      // N_NODES*HID (layer-2 pre-scaled hw)
    float* out  = hws + (size_t)N_NODES * HID;         // N_NODES*HID
    float* table= out + (size_t)N_NODES * HID;         // VOCAB*HID
    int*   bsum = (int*)(table + VOCAB * HID);         // SCAN_NB
    int*   boff = bsum + SCAN_NB;                      // SCAN_NB
    int2*  xd   = (int2*)(((uintptr_t)(boff + SCAN_NB) + 15) & ~(uintptr_t)15); // N_NODES

    const int* srcp = ei;            // edge_index row 0
    const int* dstp = ei + N_EDGES;  // edge_index row 1

    (void)hipMemsetAsync(icnt, 0, (size_t)NCOPY * N_NODES * sizeof(int), stream);

    const int EBLK = (N_EDGES + 255) / 256;            // 12500
    k_hist       <<<EBLK, 256, 0, stream>>>(dstp, icnt);
    k_merge_scan1<<<SCAN_NB, 1024, 0, stream>>>(icnt, row, dinv, bsum);
    k_scanblocks <<<1, 128, 0, stream>>>(bsum, boff);
    k_cursor     <<<(N_NODES + 255) / 256, 256, 0, stream>>>(icnt, row, boff, x, dinv, xd);
    k_scatter    <<<EBLK * NPART, 256, 0, stream>>>(srcp, dstp, icnt, csr);
    k_table      <<<(VOCAB * HID + 255) / 256, 256, 0, stream>>>(emb, W1, table);
    k_gather_t   <<<(N_NODES * HID) / 256, 256, 0, stream>>>(row, csr, xd, table, b1, W2, hws);
    k_gather     <<<(N_NODES * HID + 255) / 256, 256, 0, stream>>>(row, csr, dinv, hws, out);
    k_pool       <<<N_GRAPHS, 256, 0, stream>>>(out, batch, b2, Wc, bc, outp);
}